// Round 3
// baseline (205.523 us; speedup 1.0000x reference)
//
#include <hip/hip_runtime.h>

#define A_TOT 8400
#define NCLS  80
#define MGT   64
#define TK    13
#define EPS7  1e-7f
#define EPS9  1e-9f
#define INV_PI2 0.4052847345693511f   // 4/pi^2

__device__ __forceinline__ float ciou_clip(
    float gx1, float gy1, float gx2, float gy2, float ga, float area1,
    float px1, float py1, float px2, float py2, float pa)
{
  float w2 = px2 - px1, h2 = py2 - py1 + EPS7;
  float iw = fmaxf(fminf(gx2, px2) - fmaxf(gx1, px1), 0.f);
  float ih = fmaxf(fminf(gy2, py2) - fmaxf(gy1, py1), 0.f);
  float inter = iw * ih;
  float uni = area1 + w2 * h2 - inter + EPS7;
  float iou = inter / uni;
  float cw = fmaxf(gx2, px2) - fminf(gx1, px1);
  float ch = fmaxf(gy2, py2) - fminf(gy1, py1);
  float c2 = cw * cw + ch * ch + EPS7;
  float dx = px1 + px2 - gx1 - gx2;
  float dy = py1 + py2 - gy1 - gy2;
  float rho2 = (dx * dx + dy * dy) * 0.25f;
  float dd = pa - ga;
  float v = INV_PI2 * dd * dd;
  float alpha = v / (v - iou + (1.f + EPS7));
  float c = iou - (rho2 / c2 + v * alpha);
  return fmaxf(c, 0.f);   // overlaps = ciou.clip(0)
}

__device__ __forceinline__ unsigned long long wmax64(unsigned long long k) {
#pragma unroll
  for (int s = 32; s > 0; s >>= 1) {
    unsigned long long o = __shfl_xor(k, s, 64);
    k = (o > k) ? o : k;
  }
  return k;
}

// One block per (b,m). Computes metric = score*ciou^6 for in-gt anchors,
// exact top-13 with lax.top_k tie semantics via unique monotone u64 keys
// key = (fbits(metric)<<32) | ~a  (value desc, index asc). Scatters the
// selected positives as bit m into mask64[b,a].
__global__ __launch_bounds__(256)
void k_topk(const float* __restrict__ pd_scores,
            const float* __restrict__ pd_bboxes,
            const float* __restrict__ anc,
            const int* __restrict__ gt_labels,
            const float* __restrict__ gt_bboxes,
            const float* __restrict__ mask_gt,
            unsigned long long* __restrict__ mask64)
{
  int row = blockIdx.x;                 // b*MGT + m
  if (mask_gt[row] <= 0.f) return;      // invalid gt: no positives
  int b = row / MGT;
  int m = row - b * MGT;

  float4 g = ((const float4*)gt_bboxes)[row];
  float ga = atanf((g.z - g.x) / (g.w - g.y + EPS7));
  float area1 = (g.z - g.x) * (g.w - g.y + EPS7);
  int label = gt_labels[row];
  const float*  ps   = pd_scores + (size_t)b * A_TOT * NCLS + label;
  const float4* pb   = (const float4*)(pd_bboxes + (size_t)b * A_TOT * 4);
  const float2* anc2 = (const float2*)anc;

  // thread-local top-13 keys, sorted desc, all-register (static indices only)
  unsigned long long l[TK];
#pragma unroll
  for (int k = 0; k < TK; ++k) l[k] = 0ULL;

  for (int a = threadIdx.x; a < A_TOT; a += 256) {
    float2 an = anc2[a];
    float dmin = fminf(fminf(an.x - g.x, an.y - g.y), fminf(g.z - an.x, g.w - an.y));
    unsigned long long key = (unsigned long long)(~(unsigned)a);
    if (dmin > EPS9) {
      float4 p = pb[a];
      float pa = atanf((p.z - p.x) / (p.w - p.y + EPS7));
      float ov = ciou_clip(g.x, g.y, g.z, g.w, ga, area1, p.x, p.y, p.z, p.w, pa);
      float o2 = ov * ov;
      float metric = ps[(size_t)a * NCLS] * (o2 * o2 * o2);
      key |= ((unsigned long long)__float_as_uint(metric)) << 32;
    }
    if (key > l[TK - 1]) {              // unrolled static insertion
#pragma unroll
      for (int j = TK - 1; j > 0; --j) {
        unsigned long long prev = l[j - 1];
        l[j] = (key > prev) ? prev : ((key > l[j]) ? key : l[j]);
      }
      l[0] = (key > l[0]) ? key : l[0];
    }
  }

  int lane = threadIdx.x & 63, wid = threadIdx.x >> 6;

  // wave-level top-13 by repeated shfl-max extraction (no barriers)
  unsigned long long wres = 0ULL;
#pragma unroll
  for (int r = 0; r < TK; ++r) {
    unsigned long long w = wmax64(l[0]);
    if (lane == r) wres = w;
    if (l[0] == w) {                    // unique keys: exactly one winner
#pragma unroll
      for (int j = 0; j < TK - 1; ++j) l[j] = l[j + 1];
      l[TK - 1] = 0ULL;
    }
  }

  __shared__ unsigned long long sk[4 * TK];
  if (lane < TK) sk[wid * TK + lane] = wres;
  __syncthreads();

  if (wid == 0) {
    unsigned long long c = (lane < 4 * TK) ? sk[lane] : 0ULL;
    unsigned long long res = 0ULL;
#pragma unroll
    for (int r = 0; r < TK; ++r) {
      unsigned long long w = wmax64(c);
      if (lane == r) res = w;
      if (c == w) c = 0ULL;
    }
    if (lane < TK) {
      unsigned a = ~(unsigned)res;
      float2 an = anc2[a];
      float dmin = fminf(fminf(an.x - g.x, an.y - g.y), fminf(g.z - an.x, g.w - an.y));
      if (dmin > EPS9)                  // mask_topk * mask_in_gts * mask_gt
        atomicOr(mask64 + (size_t)b * A_TOT + a, 1ULL << m);
    }
  }
}

// Per (b,a): resolve assignment. popcount==1 -> unique gt; >1 -> argmax over
// ALL m of overlaps (first-max, matching jnp argmax). Emits tgt (-1 if bg),
// align_metric, and per-gt maxima via float-bits atomicMax (values >= 0).
__global__ __launch_bounds__(256)
void k_resolve(const float* __restrict__ pd_scores,
               const float* __restrict__ pd_bboxes,
               const int* __restrict__ gt_labels,
               const float* __restrict__ gt_bboxes,
               const unsigned long long* __restrict__ mask64,
               int* __restrict__ tgt_ws, float* __restrict__ am_ws,
               unsigned int* __restrict__ pos_al, unsigned int* __restrict__ pos_ov,
               int total)
{
  int t = blockIdx.x * 256 + threadIdx.x;
  if (t >= total) return;
  unsigned long long msk = mask64[t];
  if (msk == 0ULL) { tgt_ws[t] = -1; return; }
  int b = t / A_TOT;
  float4 p = ((const float4*)pd_bboxes)[t];
  float pa = atanf((p.z - p.x) / (p.w - p.y + EPS7));
  const float4* gb = (const float4*)gt_bboxes + b * MGT;
  int tgt; float ov;
  if (__popcll(msk) == 1) {
    tgt = __ffsll((unsigned long long)msk) - 1;
    float4 g = gb[tgt];
    float ga = atanf((g.z - g.x) / (g.w - g.y + EPS7));
    float area1 = (g.z - g.x) * (g.w - g.y + EPS7);
    ov = ciou_clip(g.x, g.y, g.z, g.w, ga, area1, p.x, p.y, p.z, p.w, pa);
  } else {
    tgt = 0; ov = -1.f;
    for (int mm = 0; mm < MGT; ++mm) {  // argmax over ALL m, first-max wins
      float4 g = gb[mm];
      float ga = atanf((g.z - g.x) / (g.w - g.y + EPS7));
      float area1 = (g.z - g.x) * (g.w - g.y + EPS7);
      float o = ciou_clip(g.x, g.y, g.z, g.w, ga, area1, p.x, p.y, p.z, p.w, pa);
      if (o > ov) { ov = o; tgt = mm; }
    }
  }
  int label = gt_labels[b * MGT + tgt];
  float sc = pd_scores[(size_t)t * NCLS + label];
  float o2 = ov * ov;
  float am = sc * (o2 * o2 * o2);
  tgt_ws[t] = tgt; am_ws[t] = am;
  atomicMax(pos_al + b * MGT + tgt, __float_as_uint(am));
  atomicMax(pos_ov + b * MGT + tgt, __float_as_uint(ov));
}

// Final outputs. Score rows written cooperatively, fully-coalesced float4.
__global__ __launch_bounds__(256)
void k_write(const int* __restrict__ tgt_ws, const float* __restrict__ am_ws,
             const unsigned int* __restrict__ pos_al,
             const unsigned int* __restrict__ pos_ov,
             const int* __restrict__ gt_labels, const float* __restrict__ gt_bboxes,
             float* __restrict__ out, int bs)
{
  __shared__ int   slab[256];
  __shared__ float snorm[256];
  int total = bs * A_TOT;
  int base = blockIdx.x * 256;
  int t = base + threadIdx.x;
  int nrows = total - base; if (nrows > 256) nrows = 256;
  size_t OFF_BOX = (size_t)total;
  size_t OFF_SCR = OFF_BOX + (size_t)total * 4;
  size_t OFF_FG  = OFF_SCR + (size_t)total * NCLS;
  size_t OFF_TGT = OFF_FG + (size_t)total;
  if (t < total) {
    int b = t / A_TOT;
    int tw = tgt_ws[t];
    bool fg = tw >= 0;
    int tgt = fg ? tw : 0;
    int gi = b * MGT + tgt;
    int lab = gt_labels[gi]; if (lab < 0) lab = 0;
    float4 box = ((const float4*)gt_bboxes)[gi];
    float nrm = 0.f;
    if (fg) {
      float pa_ = __uint_as_float(pos_al[gi]);
      float po  = __uint_as_float(pos_ov[gi]);
      nrm = am_ws[t] * po / (pa_ + EPS9);
    }
    out[t] = (float)lab;
    ((float4*)(out + OFF_BOX))[t] = box;
    out[OFF_FG + t]  = fg ? 1.f : 0.f;
    out[OFF_TGT + t] = (float)tgt;
    slab[threadIdx.x]  = lab;
    snorm[threadIdx.x] = nrm;
  }
  __syncthreads();
  float4* srow = (float4*)(out + OFF_SCR + (size_t)base * NCLS);
  int nvec = nrows * (NCLS / 4);
  for (int u = threadIdx.x; u < nvec; u += 256) {
    int i  = u / (NCLS / 4);
    int c0 = (u - i * (NCLS / 4)) * 4;
    int lb = slab[i]; float nv = snorm[i];
    float4 v;
    v.x = (lb == c0    ) ? nv : 0.f;
    v.y = (lb == c0 + 1) ? nv : 0.f;
    v.z = (lb == c0 + 2) ? nv : 0.f;
    v.w = (lb == c0 + 3) ? nv : 0.f;
    srow[u] = v;
  }
}

extern "C" void kernel_launch(void* const* d_in, const int* in_sizes, int n_in,
                              void* d_out, int out_size, void* d_ws, size_t ws_size,
                              hipStream_t stream)
{
  const float* pd_scores = (const float*)d_in[0];
  const float* pd_bboxes = (const float*)d_in[1];
  const float* anc       = (const float*)d_in[2];
  const int*   gt_labels = (const int*)d_in[3];
  const float* gt_bboxes = (const float*)d_in[4];
  const float* mask_gt   = (const float*)d_in[5];
  int bs = in_sizes[0] / (A_TOT * NCLS);
  int NA = bs * A_TOT, NM = bs * MGT;

  // workspace layout (8B-aligned first)
  unsigned long long* mask64 = (unsigned long long*)d_ws;  // NA  <- zeroed
  unsigned int* pos_al = (unsigned int*)(mask64 + NA);     // NM  <- zeroed
  unsigned int* pos_ov = pos_al + NM;                      // NM  <- zeroed
  int*   tgt_ws = (int*)(pos_ov + NM);                     // NA
  float* am_ws  = (float*)(tgt_ws + NA);                   // NA

  hipMemsetAsync(mask64, 0, (size_t)NA * 8 + (size_t)NM * 8, stream);

  k_topk<<<NM, 256, 0, stream>>>(pd_scores, pd_bboxes, anc, gt_labels, gt_bboxes,
                                 mask_gt, mask64);
  k_resolve<<<(NA + 255) / 256, 256, 0, stream>>>(pd_scores, pd_bboxes, gt_labels,
                                                  gt_bboxes, mask64, tgt_ws, am_ws,
                                                  pos_al, pos_ov, NA);
  k_write<<<(NA + 255) / 256, 256, 0, stream>>>(tgt_ws, am_ws, pos_al, pos_ov,
                                                gt_labels, gt_bboxes, (float*)d_out, bs);
}

// Round 4
// 156.373 us; speedup vs baseline: 1.3143x; 1.3143x over previous
//
#include <hip/hip_runtime.h>

#define A_TOT 8400
#define NCLS  80
#define MGT   64
#define TK    13
#define EPS7  1e-7f
#define EPS9  1e-9f
#define INV_PI2 0.4052847345693511f   // 4/pi^2

__device__ __forceinline__ float ciou_clip(
    float gx1, float gy1, float gx2, float gy2, float ga, float area1,
    float px1, float py1, float px2, float py2, float pa)
{
  float w2 = px2 - px1, h2 = py2 - py1 + EPS7;
  float iw = fmaxf(fminf(gx2, px2) - fmaxf(gx1, px1), 0.f);
  float ih = fmaxf(fminf(gy2, py2) - fmaxf(gy1, py1), 0.f);
  float inter = iw * ih;
  float uni = area1 + w2 * h2 - inter + EPS7;
  float iou = inter / uni;
  float cw = fmaxf(gx2, px2) - fminf(gx1, px1);
  float ch = fmaxf(gy2, py2) - fminf(gy1, py1);
  float c2 = cw * cw + ch * ch + EPS7;
  float dx = px1 + px2 - gx1 - gx2;
  float dy = py1 + py2 - gy1 - gy2;
  float rho2 = (dx * dx + dy * dy) * 0.25f;
  float dd = pa - ga;
  float v = INV_PI2 * dd * dd;
  float alpha = v / (v - iou + (1.f + EPS7));
  float c = iou - (rho2 / c2 + v * alpha);
  return fmaxf(c, 0.f);   // overlaps = ciou.clip(0)
}

__device__ __forceinline__ unsigned long long wmax64(unsigned long long k) {
#pragma unroll
  for (int s = 32; s > 0; s >>= 1) {
    unsigned long long o = __shfl_xor(k, s, 64);
    k = (o > k) ? o : k;
  }
  return k;
}

// atan(w/h) tables: per pred box (NA) and per gt box (NM).
__global__ void k_pre(const float* __restrict__ pd_bboxes,
                      const float* __restrict__ gt_bboxes,
                      float* __restrict__ patan, float* __restrict__ gatan,
                      int na, int nm)
{
  int t = blockIdx.x * 256 + threadIdx.x;
  if (t < na) {
    float4 bx = ((const float4*)pd_bboxes)[t];
    patan[t] = atanf((bx.z - bx.x) / (bx.w - bx.y + EPS7));
  } else if (t < na + nm) {
    int r = t - na;
    float4 bx = ((const float4*)gt_bboxes)[r];
    gatan[r] = atanf((bx.z - bx.x) / (bx.w - bx.y + EPS7));
  }
}

// One block per (b,m). Computes metric = score*ciou^6 for in-gt anchors,
// exact top-13 with lax.top_k tie semantics via unique monotone u64 keys
// key = (fbits(metric)<<32) | ~a  (value desc, index asc). Scatters the
// selected positives as bit m into mask64[b,a].
__global__ __launch_bounds__(256)
void k_topk(const float* __restrict__ pd_scores,
            const float* __restrict__ pd_bboxes,
            const float* __restrict__ anc,
            const int* __restrict__ gt_labels,
            const float* __restrict__ gt_bboxes,
            const float* __restrict__ mask_gt,
            const float* __restrict__ patan,
            const float* __restrict__ gatan,
            unsigned long long* __restrict__ mask64)
{
  int row = blockIdx.x;                 // b*MGT + m
  if (mask_gt[row] <= 0.f) return;      // invalid gt: no positives
  int b = row / MGT;
  int m = row - b * MGT;

  float4 g = ((const float4*)gt_bboxes)[row];
  float ga = gatan[row];
  float area1 = (g.z - g.x) * (g.w - g.y + EPS7);
  int label = gt_labels[row];
  const float*  ps   = pd_scores + (size_t)b * A_TOT * NCLS + label;
  const float4* pb   = (const float4*)(pd_bboxes + (size_t)b * A_TOT * 4);
  const float*  pat  = patan + (size_t)b * A_TOT;
  const float2* anc2 = (const float2*)anc;

  // thread-local top-13 keys, sorted desc, all-register (static indices only)
  unsigned long long l[TK];
#pragma unroll
  for (int k = 0; k < TK; ++k) l[k] = 0ULL;

  for (int a = threadIdx.x; a < A_TOT; a += 256) {
    float2 an = anc2[a];
    float pa = pat[a];                  // coalesced, unconditional
    float dmin = fminf(fminf(an.x - g.x, an.y - g.y), fminf(g.z - an.x, g.w - an.y));
    unsigned long long key = (unsigned long long)(~(unsigned)a);
    if (dmin > EPS9) {
      float4 p = pb[a];
      float ov = ciou_clip(g.x, g.y, g.z, g.w, ga, area1, p.x, p.y, p.z, p.w, pa);
      float o2 = ov * ov;
      float metric = ps[(size_t)a * NCLS] * (o2 * o2 * o2);
      key |= ((unsigned long long)__float_as_uint(metric)) << 32;
    }
    if (key > l[TK - 1]) {              // unrolled static insertion
#pragma unroll
      for (int j = TK - 1; j > 0; --j) {
        unsigned long long prev = l[j - 1];
        l[j] = (key > prev) ? prev : ((key > l[j]) ? key : l[j]);
      }
      l[0] = (key > l[0]) ? key : l[0];
    }
  }

  int lane = threadIdx.x & 63, wid = threadIdx.x >> 6;

  // wave-level top-13 by repeated shfl-max extraction (no barriers)
  unsigned long long wres = 0ULL;
#pragma unroll
  for (int r = 0; r < TK; ++r) {
    unsigned long long w = wmax64(l[0]);
    if (lane == r) wres = w;
    if (l[0] == w) {                    // unique keys: exactly one winner
#pragma unroll
      for (int j = 0; j < TK - 1; ++j) l[j] = l[j + 1];
      l[TK - 1] = 0ULL;
    }
  }

  __shared__ unsigned long long sk[4 * TK];
  if (lane < TK) sk[wid * TK + lane] = wres;
  __syncthreads();

  if (wid == 0) {
    unsigned long long c = (lane < 4 * TK) ? sk[lane] : 0ULL;
    unsigned long long res = 0ULL;
#pragma unroll
    for (int r = 0; r < TK; ++r) {
      unsigned long long w = wmax64(c);
      if (lane == r) res = w;
      if (c == w) c = 0ULL;
    }
    if (lane < TK) {
      unsigned a = ~(unsigned)res;
      float2 an = anc2[a];
      float dmin = fminf(fminf(an.x - g.x, an.y - g.y), fminf(g.z - an.x, g.w - an.y));
      if (dmin > EPS9)                  // mask_topk * mask_in_gts * mask_gt
        atomicOr(mask64 + (size_t)b * A_TOT + a, 1ULL << m);
    }
  }
}

// Per (b,a): bg -> tgt=-1. Single gt -> resolve inline (1 CIoU, tables).
// Multi gt -> append anchor to compacted list for wave-parallel k_multi.
__global__ __launch_bounds__(256)
void k_resolve(const float* __restrict__ pd_scores,
               const float* __restrict__ pd_bboxes,
               const int* __restrict__ gt_labels,
               const float* __restrict__ gt_bboxes,
               const float* __restrict__ patan,
               const float* __restrict__ gatan,
               const unsigned long long* __restrict__ mask64,
               int* __restrict__ tgt_ws, float* __restrict__ am_ws,
               unsigned int* __restrict__ pos_al, unsigned int* __restrict__ pos_ov,
               int* __restrict__ multi_cnt, int* __restrict__ multi_list,
               int total)
{
  int t = blockIdx.x * 256 + threadIdx.x;
  if (t >= total) return;
  unsigned long long msk = mask64[t];
  if (msk == 0ULL) { tgt_ws[t] = -1; return; }
  if (__popcll(msk) > 1) {
    int slot = atomicAdd(multi_cnt, 1);
    multi_list[slot] = t;
    return;
  }
  int b = t / A_TOT;
  int tgt = __ffsll(msk) - 1;
  int gi = b * MGT + tgt;
  float4 p = ((const float4*)pd_bboxes)[t];
  float4 g = ((const float4*)gt_bboxes)[gi];
  float area1 = (g.z - g.x) * (g.w - g.y + EPS7);
  float ov = ciou_clip(g.x, g.y, g.z, g.w, gatan[gi], area1,
                       p.x, p.y, p.z, p.w, patan[t]);
  int label = gt_labels[gi];
  float sc = pd_scores[(size_t)t * NCLS + label];
  float o2 = ov * ov;
  float am = sc * (o2 * o2 * o2);
  tgt_ws[t] = tgt; am_ws[t] = am;
  atomicMax(pos_al + gi, __float_as_uint(am));
  atomicMax(pos_ov + gi, __float_as_uint(ov));
}

// One wave per multi-assigned anchor: 64 lanes <-> 64 gts, argmax over ALL m
// of overlaps with first-max tie rule via unique key (fbits(ov)<<6)|(63-m).
__global__ __launch_bounds__(256)
void k_multi(const float* __restrict__ pd_scores,
             const float* __restrict__ pd_bboxes,
             const int* __restrict__ gt_labels,
             const float* __restrict__ gt_bboxes,
             const float* __restrict__ patan,
             const float* __restrict__ gatan,
             const int* __restrict__ multi_cnt,
             const int* __restrict__ multi_list,
             int* __restrict__ tgt_ws, float* __restrict__ am_ws,
             unsigned int* __restrict__ pos_al, unsigned int* __restrict__ pos_ov)
{
  int cnt = multi_cnt[0];
  int lane = threadIdx.x & 63;
  int wv = (blockIdx.x * 256 + threadIdx.x) >> 6;
  int nw = (gridDim.x * 256) >> 6;
  for (int i = wv; i < cnt; i += nw) {
    int t = multi_list[i];
    int b = t / A_TOT;
    float4 p = ((const float4*)pd_bboxes)[t];
    float pa = patan[t];
    int gi = b * MGT + lane;
    float4 g = ((const float4*)gt_bboxes)[gi];
    float area1 = (g.z - g.x) * (g.w - g.y + EPS7);
    float ov = ciou_clip(g.x, g.y, g.z, g.w, gatan[gi], area1,
                         p.x, p.y, p.z, p.w, pa);
    unsigned long long key =
        (((unsigned long long)__float_as_uint(ov)) << 6) | (unsigned)(63 - lane);
    unsigned long long w = wmax64(key);
    if (key == w) {                     // winner lane = argmax gt (first-max)
      int label = gt_labels[gi];
      float sc = pd_scores[(size_t)t * NCLS + label];
      float o2 = ov * ov;
      float am = sc * (o2 * o2 * o2);
      tgt_ws[t] = lane; am_ws[t] = am;
      atomicMax(pos_al + gi, __float_as_uint(am));
      atomicMax(pos_ov + gi, __float_as_uint(ov));
    }
  }
}

// Final outputs. Score rows written cooperatively, fully-coalesced float4.
__global__ __launch_bounds__(256)
void k_write(const int* __restrict__ tgt_ws, const float* __restrict__ am_ws,
             const unsigned int* __restrict__ pos_al,
             const unsigned int* __restrict__ pos_ov,
             const int* __restrict__ gt_labels, const float* __restrict__ gt_bboxes,
             float* __restrict__ out, int bs)
{
  __shared__ int   slab[256];
  __shared__ float snorm[256];
  int total = bs * A_TOT;
  int base = blockIdx.x * 256;
  int t = base + threadIdx.x;
  int nrows = total - base; if (nrows > 256) nrows = 256;
  size_t OFF_BOX = (size_t)total;
  size_t OFF_SCR = OFF_BOX + (size_t)total * 4;
  size_t OFF_FG  = OFF_SCR + (size_t)total * NCLS;
  size_t OFF_TGT = OFF_FG + (size_t)total;
  if (t < total) {
    int b = t / A_TOT;
    int tw = tgt_ws[t];
    bool fg = tw >= 0;
    int tgt = fg ? tw : 0;
    int gi = b * MGT + tgt;
    int lab = gt_labels[gi]; if (lab < 0) lab = 0;
    float4 box = ((const float4*)gt_bboxes)[gi];
    float nrm = 0.f;
    if (fg) {
      float pa_ = __uint_as_float(pos_al[gi]);
      float po  = __uint_as_float(pos_ov[gi]);
      nrm = am_ws[t] * po / (pa_ + EPS9);
    }
    out[t] = (float)lab;
    ((float4*)(out + OFF_BOX))[t] = box;
    out[OFF_FG + t]  = fg ? 1.f : 0.f;
    out[OFF_TGT + t] = (float)tgt;
    slab[threadIdx.x]  = lab;
    snorm[threadIdx.x] = nrm;
  }
  __syncthreads();
  float4* srow = (float4*)(out + OFF_SCR + (size_t)base * NCLS);
  int nvec = nrows * (NCLS / 4);
  for (int u = threadIdx.x; u < nvec; u += 256) {
    int i  = u / (NCLS / 4);
    int c0 = (u - i * (NCLS / 4)) * 4;
    int lb = slab[i]; float nv = snorm[i];
    float4 v;
    v.x = (lb == c0    ) ? nv : 0.f;
    v.y = (lb == c0 + 1) ? nv : 0.f;
    v.z = (lb == c0 + 2) ? nv : 0.f;
    v.w = (lb == c0 + 3) ? nv : 0.f;
    srow[u] = v;
  }
}

extern "C" void kernel_launch(void* const* d_in, const int* in_sizes, int n_in,
                              void* d_out, int out_size, void* d_ws, size_t ws_size,
                              hipStream_t stream)
{
  const float* pd_scores = (const float*)d_in[0];
  const float* pd_bboxes = (const float*)d_in[1];
  const float* anc       = (const float*)d_in[2];
  const int*   gt_labels = (const int*)d_in[3];
  const float* gt_bboxes = (const float*)d_in[4];
  const float* mask_gt   = (const float*)d_in[5];
  int bs = in_sizes[0] / (A_TOT * NCLS);
  int NA = bs * A_TOT, NM = bs * MGT;

  // workspace layout — zeroed region first (mask64..multi_cnt), then scratch
  unsigned long long* mask64 = (unsigned long long*)d_ws;  // NA   <- zeroed
  unsigned int* pos_al = (unsigned int*)(mask64 + NA);     // NM   <- zeroed
  unsigned int* pos_ov = pos_al + NM;                      // NM   <- zeroed
  int* multi_cnt = (int*)(pos_ov + NM);                    // 2    <- zeroed
  int*   tgt_ws = multi_cnt + 2;                           // NA
  float* am_ws  = (float*)(tgt_ws + NA);                   // NA
  float* patan  = am_ws + NA;                              // NA
  float* gatan  = patan + NA;                              // NM
  int*   multi_list = (int*)(gatan + NM);                  // NA

  hipMemsetAsync(mask64, 0, (size_t)NA * 8 + (size_t)NM * 8 + 8, stream);

  k_pre<<<(NA + NM + 255) / 256, 256, 0, stream>>>(pd_bboxes, gt_bboxes,
                                                   patan, gatan, NA, NM);
  k_topk<<<NM, 256, 0, stream>>>(pd_scores, pd_bboxes, anc, gt_labels, gt_bboxes,
                                 mask_gt, patan, gatan, mask64);
  k_resolve<<<(NA + 255) / 256, 256, 0, stream>>>(pd_scores, pd_bboxes, gt_labels,
                                                  gt_bboxes, patan, gatan, mask64,
                                                  tgt_ws, am_ws, pos_al, pos_ov,
                                                  multi_cnt, multi_list, NA);
  k_multi<<<128, 256, 0, stream>>>(pd_scores, pd_bboxes, gt_labels, gt_bboxes,
                                   patan, gatan, multi_cnt, multi_list,
                                   tgt_ws, am_ws, pos_al, pos_ov);
  k_write<<<(NA + 255) / 256, 256, 0, stream>>>(tgt_ws, am_ws, pos_al, pos_ov,
                                                gt_labels, gt_bboxes, (float*)d_out, bs);
}

// Round 5
// 132.733 us; speedup vs baseline: 1.5484x; 1.1781x over previous
//
#include <hip/hip_runtime.h>

#define A_TOT 8400
#define NCLS  80
#define MGT   64
#define TK    13
#define EPS7  1e-7f
#define EPS9  1e-9f
#define INV_PI2 0.4052847345693511f   // 4/pi^2

__device__ __forceinline__ float ciou_clip(
    float gx1, float gy1, float gx2, float gy2, float ga, float area1,
    float px1, float py1, float px2, float py2, float pa)
{
  float w2 = px2 - px1, h2 = py2 - py1 + EPS7;
  float iw = fmaxf(fminf(gx2, px2) - fmaxf(gx1, px1), 0.f);
  float ih = fmaxf(fminf(gy2, py2) - fmaxf(gy1, py1), 0.f);
  float inter = iw * ih;
  float uni = area1 + w2 * h2 - inter + EPS7;
  float iou = inter / uni;
  float cw = fmaxf(gx2, px2) - fminf(gx1, px1);
  float ch = fmaxf(gy2, py2) - fminf(gy1, py1);
  float c2 = cw * cw + ch * ch + EPS7;
  float dx = px1 + px2 - gx1 - gx2;
  float dy = py1 + py2 - gy1 - gy2;
  float rho2 = (dx * dx + dy * dy) * 0.25f;
  float dd = pa - ga;
  float v = INV_PI2 * dd * dd;
  float alpha = v / (v - iou + (1.f + EPS7));
  float c = iou - (rho2 / c2 + v * alpha);
  return fmaxf(c, 0.f);   // overlaps = ciou.clip(0)
}

__device__ __forceinline__ unsigned long long wmax64(unsigned long long k) {
#pragma unroll
  for (int s = 32; s > 0; s >>= 1) {
    unsigned long long o = __shfl_xor(k, s, 64);
    k = (o > k) ? o : k;
  }
  return k;
}

// atan(w/h) tables: per pred box (na) and per gt box (nm).
__global__ void k_pre(const float* __restrict__ pd_bboxes,
                      const float* __restrict__ gt_bboxes,
                      float* __restrict__ patan, float* __restrict__ gatan,
                      int na, int nm)
{
  int t = blockIdx.x * 256 + threadIdx.x;
  if (t < na) {
    float4 bx = ((const float4*)pd_bboxes)[t];
    patan[t] = atanf((bx.z - bx.x) / (bx.w - bx.y + EPS7));
  } else if (t < na + nm) {
    int r = t - na;
    float4 bx = ((const float4*)gt_bboxes)[r];
    gatan[r] = atanf((bx.z - bx.x) / (bx.w - bx.y + EPS7));
  }
}

// One WAVE per (b,m) row. Candidate set = {anchors 0..63} U {grid cells whose
// center lies in the gt box, enumerated in closed form per scale}. This
// provably contains lax.top_k(metrics,13): positives are in the rectangles;
// zero-metric tie-fills (value 0, index asc) are always within the first 64
// (>=51 zero-metric anchors there). Widened integer bounds + exact float
// re-test keep selection bit-exact. Winners post-masked by in-box (dmin>EPS9)
// and scattered as bit m into mask64[b,a]. No LDS, no barriers.
__global__ __launch_bounds__(64)
void k_topk(const float* __restrict__ pd_scores,
            const float* __restrict__ pd_bboxes,
            const float* __restrict__ anc,
            const int* __restrict__ gt_labels,
            const float* __restrict__ gt_bboxes,
            const float* __restrict__ mask_gt,
            const float* __restrict__ patan,
            const float* __restrict__ gatan,
            unsigned long long* __restrict__ mask64)
{
  int row = blockIdx.x;                 // b*MGT + m
  if (mask_gt[row] <= 0.f) return;      // invalid gt: no positives
  int b = row >> 6;
  int m = row & 63;
  int lane = threadIdx.x;

  float4 g = ((const float4*)gt_bboxes)[row];
  float ga = gatan[row];
  float area1 = (g.z - g.x) * (g.w - g.y + EPS7);
  int label = gt_labels[row];
  const float*  ps   = pd_scores + (size_t)b * A_TOT * NCLS + label;
  const float4* pb   = (const float4*)(pd_bboxes + (size_t)b * A_TOT * 4);
  const float*  pat  = patan + (size_t)b * A_TOT;
  const float2* anc2 = (const float2*)anc;

  unsigned long long l[TK];
#pragma unroll
  for (int k = 0; k < TK; ++k) l[k] = 0ULL;

  auto insert = [&](unsigned long long key) {
    if (key > l[TK - 1]) {
#pragma unroll
      for (int j = TK - 1; j > 0; --j) {
        unsigned long long prev = l[j - 1];
        l[j] = (key > prev) ? prev : ((key > l[j]) ? key : l[j]);
      }
      l[0] = (key > l[0]) ? key : l[0];
    }
  };
  auto metric_key = [&](int a, float ax, float ay) -> unsigned long long {
    // exact in-box test + metric; returns full key (zero value if out-of-box)
    float dmin = fminf(fminf(ax - g.x, ay - g.y), fminf(g.z - ax, g.w - ay));
    unsigned long long key = (unsigned long long)(~(unsigned)a);
    if (dmin > EPS9) {
      float4 p = pb[a];
      float ov = ciou_clip(g.x, g.y, g.z, g.w, ga, area1, p.x, p.y, p.z, p.w, pat[a]);
      float o2 = ov * ov;
      float metric = ps[(size_t)a * NCLS] * (o2 * o2 * o2);
      key |= ((unsigned long long)__float_as_uint(metric)) << 32;
    }
    return key;
  };

  // pass 1: anchors 0..63 (zero-pool for tie-fills; also covers rect cells <64)
  {
    float2 an = anc2[lane];
    insert(metric_key(lane, an.x, an.y));
  }

  // pass 2: per-scale rectangle enumeration (skip a<64: already covered)
  const int   ns[3] = {80, 40, 20};
  const float ss[3] = {8.f, 16.f, 32.f};
  const int   bb[3] = {0, 6400, 8000};
#pragma unroll
  for (int sc = 0; sc < 3; ++sc) {
    int n = ns[sc]; float s = ss[sc]; int base = bb[sc];
    float inv_s = 1.f / s;              // power of two: exact
    int xlo = max(0,     (int)floorf(g.x * inv_s - 0.5f));
    int xhi = min(n - 1, (int)ceilf (g.z * inv_s - 0.5f));
    int ylo = max(0,     (int)floorf(g.y * inv_s - 0.5f));
    int yhi = min(n - 1, (int)ceilf (g.w * inv_s - 0.5f));
    int nx = xhi - xlo + 1, ny = yhi - ylo + 1;
    if (nx <= 0 || ny <= 0) continue;
    int tot = nx * ny;
    float invnx = 1.f / (float)nx;
    for (int r = lane; r < tot; r += 64) {
      int q  = (int)floorf(((float)r + 0.5f) * invnx);  // r/nx exact (see note)
      int ix = xlo + (r - q * nx);
      int iy = ylo + q;
      int a = base + iy * n + ix;
      if (a < 64) continue;
      float ax = ((float)ix + 0.5f) * s;  // exact: s is power of two
      float ay = ((float)iy + 0.5f) * s;
      float dmin = fminf(fminf(ax - g.x, ay - g.y), fminf(g.z - ax, g.w - ay));
      if (dmin > EPS9) {
        float4 p = pb[a];
        float ov = ciou_clip(g.x, g.y, g.z, g.w, ga, area1, p.x, p.y, p.z, p.w, pat[a]);
        float o2 = ov * ov;
        float metric = ps[(size_t)a * NCLS] * (o2 * o2 * o2);
        insert((((unsigned long long)__float_as_uint(metric)) << 32) |
               (unsigned long long)(~(unsigned)a));
      }
      // out-of-box rect cells (a>=64) can never enter the global top-13:
      // the 64 pass-1 keys all dominate them.
    }
  }

  // wave top-13 by repeated shfl-max extraction (keys unique: distinct ~a)
  unsigned long long res = 0ULL;
#pragma unroll
  for (int r = 0; r < TK; ++r) {
    unsigned long long w = wmax64(l[0]);
    if (lane == r) res = w;
    if (l[0] == w) {
#pragma unroll
      for (int j = 0; j < TK - 1; ++j) l[j] = l[j + 1];
      l[TK - 1] = 0ULL;
    }
  }

  if (lane < TK) {
    unsigned a = ~(unsigned)res;
    float2 an = anc2[a];
    float dmin = fminf(fminf(an.x - g.x, an.y - g.y), fminf(g.z - an.x, g.w - an.y));
    if (dmin > EPS9)                    // mask_topk * mask_in_gts * mask_gt
      atomicOr(mask64 + (size_t)b * A_TOT + a, 1ULL << m);
  }
}

// Per (b,a): bg -> tgt=-1. Single gt -> resolve inline (1 CIoU, tables).
// Multi gt -> whole-wave cooperative argmax (64 lanes <-> 64 gts) via ballot,
// first-max tie rule through unique key (fbits(ov)<<6)|(63-m).
__global__ __launch_bounds__(256)
void k_resolve(const float* __restrict__ pd_scores,
               const float* __restrict__ pd_bboxes,
               const int* __restrict__ gt_labels,
               const float* __restrict__ gt_bboxes,
               const float* __restrict__ patan,
               const float* __restrict__ gatan,
               const unsigned long long* __restrict__ mask64,
               int* __restrict__ tgt_ws, float* __restrict__ am_ws,
               unsigned int* __restrict__ pos_al, unsigned int* __restrict__ pos_ov,
               int total)
{
  int t = blockIdx.x * 256 + threadIdx.x;
  bool valid = t < total;
  unsigned long long msk = valid ? mask64[t] : 0ULL;
  int pc = __popcll(msk);
  float4 p = make_float4(0.f, 0.f, 0.f, 0.f);
  float pa_own = 0.f;
  if (valid && pc >= 1) {
    p = ((const float4*)pd_bboxes)[t];
    pa_own = patan[t];
  }
  if (valid && pc == 0) tgt_ws[t] = -1;
  if (valid && pc == 1) {
    int b = t / A_TOT;
    int tgt = __ffsll(msk) - 1;
    int gi = b * MGT + tgt;
    float4 g = ((const float4*)gt_bboxes)[gi];
    float area1 = (g.z - g.x) * (g.w - g.y + EPS7);
    float ov = ciou_clip(g.x, g.y, g.z, g.w, gatan[gi], area1,
                         p.x, p.y, p.z, p.w, pa_own);
    int label = gt_labels[gi];
    float sc = pd_scores[(size_t)t * NCLS + label];
    float o2 = ov * ov;
    float am = sc * (o2 * o2 * o2);
    tgt_ws[t] = tgt; am_ws[t] = am;
    atomicMax(pos_al + gi, __float_as_uint(am));
    atomicMax(pos_ov + gi, __float_as_uint(ov));
  }
  unsigned long long mb = __ballot(valid && pc > 1);
  int lane = threadIdx.x & 63;
  while (mb) {
    int src = __ffsll(mb) - 1; mb &= mb - 1;
    int   tt  = __shfl(t, src);
    float px1 = __shfl(p.x, src), py1 = __shfl(p.y, src);
    float px2 = __shfl(p.z, src), py2 = __shfl(p.w, src);
    float pa  = __shfl(pa_own, src);
    int bb2 = tt / A_TOT;
    int gi = bb2 * MGT + lane;
    float4 g = ((const float4*)gt_bboxes)[gi];
    float area1 = (g.z - g.x) * (g.w - g.y + EPS7);
    float ov = ciou_clip(g.x, g.y, g.z, g.w, gatan[gi], area1,
                         px1, py1, px2, py2, pa);
    unsigned long long key =
        (((unsigned long long)__float_as_uint(ov)) << 6) | (unsigned)(63 - lane);
    unsigned long long w = wmax64(key);
    if (key == w) {                     // winner lane = argmax gt (first-max)
      int label = gt_labels[gi];
      float sc = pd_scores[(size_t)tt * NCLS + label];
      float o2 = ov * ov;
      float am = sc * (o2 * o2 * o2);
      tgt_ws[tt] = lane; am_ws[tt] = am;
      atomicMax(pos_al + gi, __float_as_uint(am));
      atomicMax(pos_ov + gi, __float_as_uint(ov));
    }
  }
}

// Final outputs. Score rows written cooperatively, fully-coalesced float4.
__global__ __launch_bounds__(256)
void k_write(const int* __restrict__ tgt_ws, const float* __restrict__ am_ws,
             const unsigned int* __restrict__ pos_al,
             const unsigned int* __restrict__ pos_ov,
             const int* __restrict__ gt_labels, const float* __restrict__ gt_bboxes,
             float* __restrict__ out, int bs)
{
  __shared__ int   slab[256];
  __shared__ float snorm[256];
  int total = bs * A_TOT;
  int base = blockIdx.x * 256;
  int t = base + threadIdx.x;
  int nrows = total - base; if (nrows > 256) nrows = 256;
  size_t OFF_BOX = (size_t)total;
  size_t OFF_SCR = OFF_BOX + (size_t)total * 4;
  size_t OFF_FG  = OFF_SCR + (size_t)total * NCLS;
  size_t OFF_TGT = OFF_FG + (size_t)total;
  if (t < total) {
    int b = t / A_TOT;
    int tw = tgt_ws[t];
    bool fg = tw >= 0;
    int tgt = fg ? tw : 0;
    int gi = b * MGT + tgt;
    int lab = gt_labels[gi]; if (lab < 0) lab = 0;
    float4 box = ((const float4*)gt_bboxes)[gi];
    float nrm = 0.f;
    if (fg) {
      float pa_ = __uint_as_float(pos_al[gi]);
      float po  = __uint_as_float(pos_ov[gi]);
      nrm = am_ws[t] * po / (pa_ + EPS9);
    }
    out[t] = (float)lab;
    ((float4*)(out + OFF_BOX))[t] = box;
    out[OFF_FG + t]  = fg ? 1.f : 0.f;
    out[OFF_TGT + t] = (float)tgt;
    slab[threadIdx.x]  = lab;
    snorm[threadIdx.x] = nrm;
  }
  __syncthreads();
  float4* srow = (float4*)(out + OFF_SCR + (size_t)base * NCLS);
  int nvec = nrows * (NCLS / 4);
  for (int u = threadIdx.x; u < nvec; u += 256) {
    int i  = u / (NCLS / 4);
    int c0 = (u - i * (NCLS / 4)) * 4;
    int lb = slab[i]; float nv = snorm[i];
    float4 v;
    v.x = (lb == c0    ) ? nv : 0.f;
    v.y = (lb == c0 + 1) ? nv : 0.f;
    v.z = (lb == c0 + 2) ? nv : 0.f;
    v.w = (lb == c0 + 3) ? nv : 0.f;
    srow[u] = v;
  }
}

extern "C" void kernel_launch(void* const* d_in, const int* in_sizes, int n_in,
                              void* d_out, int out_size, void* d_ws, size_t ws_size,
                              hipStream_t stream)
{
  const float* pd_scores = (const float*)d_in[0];
  const float* pd_bboxes = (const float*)d_in[1];
  const float* anc       = (const float*)d_in[2];
  const int*   gt_labels = (const int*)d_in[3];
  const float* gt_bboxes = (const float*)d_in[4];
  const float* mask_gt   = (const float*)d_in[5];
  int bs = in_sizes[0] / (A_TOT * NCLS);
  int NA = bs * A_TOT, NM = bs * MGT;

  // workspace layout — zeroed region first, then scratch
  unsigned long long* mask64 = (unsigned long long*)d_ws;  // NA   <- zeroed
  unsigned int* pos_al = (unsigned int*)(mask64 + NA);     // NM   <- zeroed
  unsigned int* pos_ov = pos_al + NM;                      // NM   <- zeroed
  int*   tgt_ws = (int*)(pos_ov + NM);                     // NA
  float* am_ws  = (float*)(tgt_ws + NA);                   // NA
  float* patan  = am_ws + NA;                              // NA
  float* gatan  = patan + NA;                              // NM

  hipMemsetAsync(mask64, 0, (size_t)NA * 8 + (size_t)NM * 8, stream);

  k_pre<<<(NA + NM + 255) / 256, 256, 0, stream>>>(pd_bboxes, gt_bboxes,
                                                   patan, gatan, NA, NM);
  k_topk<<<NM, 64, 0, stream>>>(pd_scores, pd_bboxes, anc, gt_labels, gt_bboxes,
                                mask_gt, patan, gatan, mask64);
  k_resolve<<<(NA + 255) / 256, 256, 0, stream>>>(pd_scores, pd_bboxes, gt_labels,
                                                  gt_bboxes, patan, gatan, mask64,
                                                  tgt_ws, am_ws, pos_al, pos_ov, NA);
  k_write<<<(NA + 255) / 256, 256, 0, stream>>>(tgt_ws, am_ws, pos_al, pos_ov,
                                                gt_labels, gt_bboxes, (float*)d_out, bs);
}

// Round 6
// 128.702 us; speedup vs baseline: 1.5969x; 1.0313x over previous
//
#include <hip/hip_runtime.h>

#define A_TOT 8400
#define NCLS  80
#define MGT   64
#define TK    13
#define NT    256                       // k_topk block size / pass-1 pool
#define EPS7  1e-7f
#define EPS9  1e-9f
#define INV_PI2 0.4052847345693511f     // 4/pi^2

__device__ __forceinline__ float ciou_clip(
    float gx1, float gy1, float gx2, float gy2, float ga, float area1,
    float px1, float py1, float px2, float py2, float pa)
{
  float w2 = px2 - px1, h2 = py2 - py1 + EPS7;
  float iw = fmaxf(fminf(gx2, px2) - fmaxf(gx1, px1), 0.f);
  float ih = fmaxf(fminf(gy2, py2) - fmaxf(gy1, py1), 0.f);
  float inter = iw * ih;
  float uni = area1 + w2 * h2 - inter + EPS7;
  float iou = inter / uni;
  float cw = fmaxf(gx2, px2) - fminf(gx1, px1);
  float ch = fmaxf(gy2, py2) - fminf(gy1, py1);
  float c2 = cw * cw + ch * ch + EPS7;
  float dx = px1 + px2 - gx1 - gx2;
  float dy = py1 + py2 - gy1 - gy2;
  float rho2 = (dx * dx + dy * dy) * 0.25f;
  float dd = pa - ga;
  float v = INV_PI2 * dd * dd;
  float alpha = v / (v - iou + (1.f + EPS7));
  float c = iou - (rho2 / c2 + v * alpha);
  return fmaxf(c, 0.f);   // overlaps = ciou.clip(0)
}

__device__ __forceinline__ unsigned long long wmax64(unsigned long long k) {
#pragma unroll
  for (int s = 32; s > 0; s >>= 1) {
    unsigned long long o = __shfl_xor(k, s, 64);
    k = (o > k) ? o : k;
  }
  return k;
}

// One block (4 waves) per (b,m) row. Candidate set = {anchors 0..NT-1} U
// {grid cells whose center lies in the gt box, closed-form per scale}.
// Contains lax.top_k(metrics,13) provably: positives are in the rectangles;
// zero-metric tie-fills (value 0, index asc) live in the pass-1 pool whose NT
// keys dominate every excluded (out-of-box, a>=NT) anchor key. Winners
// post-masked by in-box (dmin>EPS9), scattered as bit m into mask64[b,a].
__global__ __launch_bounds__(NT)
void k_topk(const float* __restrict__ pd_scores,
            const float* __restrict__ pd_bboxes,
            const float* __restrict__ anc,
            const int* __restrict__ gt_labels,
            const float* __restrict__ gt_bboxes,
            const float* __restrict__ mask_gt,
            unsigned long long* __restrict__ mask64)
{
  int row = blockIdx.x;                 // b*MGT + m
  if (mask_gt[row] <= 0.f) return;      // uniform per block
  int b = row >> 6;
  int m = row & 63;
  int tid = threadIdx.x, lane = tid & 63, wid = tid >> 6;

  float4 g = ((const float4*)gt_bboxes)[row];
  float ga = atanf((g.z - g.x) / (g.w - g.y + EPS7));
  float area1 = (g.z - g.x) * (g.w - g.y + EPS7);
  int label = gt_labels[row];
  const float*  ps   = pd_scores + (size_t)b * A_TOT * NCLS + label;
  const float4* pb   = (const float4*)(pd_bboxes + (size_t)b * A_TOT * 4);
  const float2* anc2 = (const float2*)anc;

  unsigned long long l[TK];
#pragma unroll
  for (int k = 0; k < TK; ++k) l[k] = 0ULL;

  auto insert = [&](unsigned long long key) {
    if (key > l[TK - 1]) {
#pragma unroll
      for (int j = TK - 1; j > 0; --j) {
        unsigned long long prev = l[j - 1];
        l[j] = (key > prev) ? prev : ((key > l[j]) ? key : l[j]);
      }
      l[0] = (key > l[0]) ? key : l[0];
    }
  };
  auto eval_inbox = [&](int a) -> unsigned long long {
    // caller guarantees in-box; full metric key
    float4 p = pb[a];
    float pa = atanf((p.z - p.x) / (p.w - p.y + EPS7));
    float ov = ciou_clip(g.x, g.y, g.z, g.w, ga, area1, p.x, p.y, p.z, p.w, pa);
    float o2 = ov * ov;
    float metric = ps[(size_t)a * NCLS] * (o2 * o2 * o2);
    return (((unsigned long long)__float_as_uint(metric)) << 32) |
           (unsigned long long)(~(unsigned)a);
  };

  // pass 1: anchors 0..NT-1 (zero-pool for tie-fills; covers rect cells < NT)
  {
    int a = tid;
    float2 an = anc2[a];
    float dmin = fminf(fminf(an.x - g.x, an.y - g.y), fminf(g.z - an.x, g.w - an.y));
    unsigned long long key = (unsigned long long)(~(unsigned)a);
    if (dmin > EPS9) key = eval_inbox(a);
    insert(key);
  }

  // pass 2: per-scale rectangle enumeration (skip a<NT: already covered)
  const int   ns[3] = {80, 40, 20};
  const float ss[3] = {8.f, 16.f, 32.f};
  const int   bb[3] = {0, 6400, 8000};
#pragma unroll
  for (int sc = 0; sc < 3; ++sc) {
    int n = ns[sc]; float s = ss[sc]; int base = bb[sc];
    float inv_s = 1.f / s;              // power of two: exact
    int xlo = max(0,     (int)floorf(g.x * inv_s - 0.5f));
    int xhi = min(n - 1, (int)ceilf (g.z * inv_s - 0.5f));
    int ylo = max(0,     (int)floorf(g.y * inv_s - 0.5f));
    int yhi = min(n - 1, (int)ceilf (g.w * inv_s - 0.5f));
    int nx = xhi - xlo + 1, ny = yhi - ylo + 1;
    if (nx <= 0 || ny <= 0) continue;
    int tot = nx * ny;
    float invnx = 1.f / (float)nx;
    for (int r = tid; r < tot; r += NT) {
      int q  = (int)floorf(((float)r + 0.5f) * invnx);  // exact: margin 0.5/nx
      int ix = xlo + (r - q * nx);
      int iy = ylo + q;
      int a = base + iy * n + ix;
      if (a < NT) continue;
      float ax = ((float)ix + 0.5f) * s;  // exact: s is a power of two
      float ay = ((float)iy + 0.5f) * s;
      float dmin = fminf(fminf(ax - g.x, ay - g.y), fminf(g.z - ax, g.w - ay));
      if (dmin > EPS9) insert(eval_inbox(a));
      // out-of-box cells with a>=NT can never reach the top-13: all NT
      // pass-1 keys dominate them.
    }
  }

  // per-wave top-13 by repeated shfl-max extraction (keys unique: distinct ~a)
  __shared__ unsigned long long sk[4 * TK];
  unsigned long long wres = 0ULL;
#pragma unroll
  for (int r = 0; r < TK; ++r) {
    unsigned long long w = wmax64(l[0]);
    if (lane == r) wres = w;
    if (l[0] == w) {
#pragma unroll
      for (int j = 0; j < TK - 1; ++j) l[j] = l[j + 1];
      l[TK - 1] = 0ULL;
    }
  }
  if (lane < TK) sk[wid * TK + lane] = wres;
  __syncthreads();

  if (wid == 0) {
    unsigned long long c = (lane < 4 * TK) ? sk[lane] : 0ULL;
    unsigned long long res = 0ULL;
#pragma unroll
    for (int r = 0; r < TK; ++r) {
      unsigned long long w = wmax64(c);
      if (lane == r) res = w;
      if (c == w) c = 0ULL;
    }
    if (lane < TK) {
      unsigned a = ~(unsigned)res;
      float2 an = anc2[a];
      float dmin = fminf(fminf(an.x - g.x, an.y - g.y), fminf(g.z - an.x, g.w - an.y));
      if (dmin > EPS9)                  // mask_topk * mask_in_gts * mask_gt
        atomicOr(mask64 + (size_t)b * A_TOT + a, 1ULL << m);
    }
  }
}

// Per (b,a): bg -> tgt=-1. Single gt -> resolve inline (1 CIoU). Multi gt ->
// whole-wave cooperative argmax (64 lanes <-> 64 gts) via ballot, first-max
// tie rule through unique key (fbits(ov)<<6)|(63-m). atan inline everywhere.
__global__ __launch_bounds__(256)
void k_resolve(const float* __restrict__ pd_scores,
               const float* __restrict__ pd_bboxes,
               const int* __restrict__ gt_labels,
               const float* __restrict__ gt_bboxes,
               const unsigned long long* __restrict__ mask64,
               int* __restrict__ tgt_ws, float* __restrict__ am_ws,
               unsigned int* __restrict__ pos_al, unsigned int* __restrict__ pos_ov,
               int total)
{
  int t = blockIdx.x * 256 + threadIdx.x;
  bool valid = t < total;
  unsigned long long msk = valid ? mask64[t] : 0ULL;
  int pc = __popcll(msk);
  float4 p = make_float4(0.f, 0.f, 0.f, 0.f);
  float pa_own = 0.f;
  if (valid && pc >= 1) {
    p = ((const float4*)pd_bboxes)[t];
    pa_own = atanf((p.z - p.x) / (p.w - p.y + EPS7));
  }
  if (valid && pc == 0) tgt_ws[t] = -1;
  if (valid && pc == 1) {
    int b = t / A_TOT;
    int tgt = __ffsll(msk) - 1;
    int gi = b * MGT + tgt;
    float4 g = ((const float4*)gt_bboxes)[gi];
    float ga = atanf((g.z - g.x) / (g.w - g.y + EPS7));
    float area1 = (g.z - g.x) * (g.w - g.y + EPS7);
    float ov = ciou_clip(g.x, g.y, g.z, g.w, ga, area1,
                         p.x, p.y, p.z, p.w, pa_own);
    int label = gt_labels[gi];
    float sc = pd_scores[(size_t)t * NCLS + label];
    float o2 = ov * ov;
    float am = sc * (o2 * o2 * o2);
    tgt_ws[t] = tgt; am_ws[t] = am;
    atomicMax(pos_al + gi, __float_as_uint(am));
    atomicMax(pos_ov + gi, __float_as_uint(ov));
  }
  unsigned long long mb = __ballot(valid && pc > 1);
  int lane = threadIdx.x & 63;
  while (mb) {
    int src = __ffsll(mb) - 1; mb &= mb - 1;
    int   tt  = __shfl(t, src);
    float px1 = __shfl(p.x, src), py1 = __shfl(p.y, src);
    float px2 = __shfl(p.z, src), py2 = __shfl(p.w, src);
    float pa  = __shfl(pa_own, src);
    int bb2 = tt / A_TOT;
    int gi = bb2 * MGT + lane;
    float4 g = ((const float4*)gt_bboxes)[gi];
    float ga = atanf((g.z - g.x) / (g.w - g.y + EPS7));
    float area1 = (g.z - g.x) * (g.w - g.y + EPS7);
    float ov = ciou_clip(g.x, g.y, g.z, g.w, ga, area1,
                         px1, py1, px2, py2, pa);
    unsigned long long key =
        (((unsigned long long)__float_as_uint(ov)) << 6) | (unsigned)(63 - lane);
    unsigned long long w = wmax64(key);
    if (key == w) {                     // winner lane = argmax gt (first-max)
      int label = gt_labels[gi];
      float sc = pd_scores[(size_t)tt * NCLS + label];
      float o2 = ov * ov;
      float am = sc * (o2 * o2 * o2);
      tgt_ws[tt] = lane; am_ws[tt] = am;
      atomicMax(pos_al + gi, __float_as_uint(am));
      atomicMax(pos_ov + gi, __float_as_uint(ov));
    }
  }
}

// Final outputs. Score rows written cooperatively, fully-coalesced float4.
__global__ __launch_bounds__(256)
void k_write(const int* __restrict__ tgt_ws, const float* __restrict__ am_ws,
             const unsigned int* __restrict__ pos_al,
             const unsigned int* __restrict__ pos_ov,
             const int* __restrict__ gt_labels, const float* __restrict__ gt_bboxes,
             float* __restrict__ out, int bs)
{
  __shared__ int   slab[256];
  __shared__ float snorm[256];
  int total = bs * A_TOT;
  int base = blockIdx.x * 256;
  int t = base + threadIdx.x;
  int nrows = total - base; if (nrows > 256) nrows = 256;
  size_t OFF_BOX = (size_t)total;
  size_t OFF_SCR = OFF_BOX + (size_t)total * 4;
  size_t OFF_FG  = OFF_SCR + (size_t)total * NCLS;
  size_t OFF_TGT = OFF_FG + (size_t)total;
  if (t < total) {
    int b = t / A_TOT;
    int tw = tgt_ws[t];
    bool fg = tw >= 0;
    int tgt = fg ? tw : 0;
    int gi = b * MGT + tgt;
    int lab = gt_labels[gi]; if (lab < 0) lab = 0;
    float4 box = ((const float4*)gt_bboxes)[gi];
    float nrm = 0.f;
    if (fg) {
      float pa_ = __uint_as_float(pos_al[gi]);
      float po  = __uint_as_float(pos_ov[gi]);
      nrm = am_ws[t] * po / (pa_ + EPS9);
    }
    out[t] = (float)lab;
    ((float4*)(out + OFF_BOX))[t] = box;
    out[OFF_FG + t]  = fg ? 1.f : 0.f;
    out[OFF_TGT + t] = (float)tgt;
    slab[threadIdx.x]  = lab;
    snorm[threadIdx.x] = nrm;
  }
  __syncthreads();
  float4* srow = (float4*)(out + OFF_SCR + (size_t)base * NCLS);
  int nvec = nrows * (NCLS / 4);
  for (int u = threadIdx.x; u < nvec; u += 256) {
    int i  = u / (NCLS / 4);
    int c0 = (u - i * (NCLS / 4)) * 4;
    int lb = slab[i]; float nv = snorm[i];
    float4 v;
    v.x = (lb == c0    ) ? nv : 0.f;
    v.y = (lb == c0 + 1) ? nv : 0.f;
    v.z = (lb == c0 + 2) ? nv : 0.f;
    v.w = (lb == c0 + 3) ? nv : 0.f;
    srow[u] = v;
  }
}

extern "C" void kernel_launch(void* const* d_in, const int* in_sizes, int n_in,
                              void* d_out, int out_size, void* d_ws, size_t ws_size,
                              hipStream_t stream)
{
  const float* pd_scores = (const float*)d_in[0];
  const float* pd_bboxes = (const float*)d_in[1];
  const float* anc       = (const float*)d_in[2];
  const int*   gt_labels = (const int*)d_in[3];
  const float* gt_bboxes = (const float*)d_in[4];
  const float* mask_gt   = (const float*)d_in[5];
  int bs = in_sizes[0] / (A_TOT * NCLS);
  int NA = bs * A_TOT, NM = bs * MGT;

  // workspace layout — zeroed region first, then scratch
  unsigned long long* mask64 = (unsigned long long*)d_ws;  // NA   <- zeroed
  unsigned int* pos_al = (unsigned int*)(mask64 + NA);     // NM   <- zeroed
  unsigned int* pos_ov = pos_al + NM;                      // NM   <- zeroed
  int*   tgt_ws = (int*)(pos_ov + NM);                     // NA
  float* am_ws  = (float*)(tgt_ws + NA);                   // NA

  hipMemsetAsync(mask64, 0, (size_t)NA * 8 + (size_t)NM * 8, stream);

  k_topk<<<NM, NT, 0, stream>>>(pd_scores, pd_bboxes, anc, gt_labels, gt_bboxes,
                                mask_gt, mask64);
  k_resolve<<<(NA + 255) / 256, 256, 0, stream>>>(pd_scores, pd_bboxes, gt_labels,
                                                  gt_bboxes, mask64,
                                                  tgt_ws, am_ws, pos_al, pos_ov, NA);
  k_write<<<(NA + 255) / 256, 256, 0, stream>>>(tgt_ws, am_ws, pos_al, pos_ov,
                                                gt_labels, gt_bboxes, (float*)d_out, bs);
}